// Round 1
// baseline (3170.495 us; speedup 1.0000x reference)
//
#include <hip/hip_runtime.h>
#include <math.h>

// ---------------------------------------------------------------------------
// Problem: 2-step recurrent attention cell, N=8, I=128, C=Hc=A=P=O=256,
// H=W=40 (Q=1600), VALID 3x3 -> 38x38 (D=1444). fp32 throughout.
//
// Key algebraic facts exploited (exact, not approximations):
//  * step1 h = broadcast(h0) is spatially uniform  ->
//      k_h/v_h constant over d;  (a=1,b=1) softmax uniform -> a11 = v_h
//      q_h has 9 distinct values (3x3 SAME-padding validity classes)
//  * => h_new piecewise-constant over 9 classes (rows {0},{1..38},{39} x cols)
//  * => step2 k_h2/v_h2 piecewise-constant over 9 key classes,
//      multiplicities {1,36,1} x {1,36,1}  -> (a=0,b=1) attention collapses
//  * step2 q_h / gates dead; step1 a_x / out dead.
// Heavy work left: q_x/k_x/v_x convs (45 GF), (a=0,b=0) attention (19 GF),
// out conv (5 GF). All run through one generic strided fp32 GEMM.
// ---------------------------------------------------------------------------

// ---------------- generic tiled GEMM ----------------
// Y[b](m,n) = sum_k A[b](m,k)*B[b](k,n) (+ bias[m])
// 64x64 tile, 256 threads, 4x4 per thread, KB=16.
// aMc: A-tile loader walks m contiguously (use when sAm==1), else k (sAk==1).
// bNc: same for B along n vs k.
__global__ __launch_bounds__(256) void gemm64(
    const float* __restrict__ A, long sAm, long sAk, long sAb,
    const float* __restrict__ B, long sBk, long sBn, long sBb,
    float* __restrict__ Y, long sYm, long sYn, long sYb,
    const float* __restrict__ bias,
    int M, int Nn, int K, int aMc, int bNc)
{
  __shared__ __align__(16) float As[16][68];   // +4 pad: k-contig writes 2-way only
  __shared__ __align__(16) float Bs[16][68];
  const int bz = blockIdx.z;
  A += (long)bz * sAb; B += (long)bz * sBb; Y += (long)bz * sYb;
  const int m0 = blockIdx.y * 64, n0 = blockIdx.x * 64;
  const int tid = threadIdx.x;
  const int tx = tid & 15, ty = tid >> 4;
  float acc[4][4] = {{0.f, 0.f, 0.f, 0.f}, {0.f, 0.f, 0.f, 0.f},
                     {0.f, 0.f, 0.f, 0.f}, {0.f, 0.f, 0.f, 0.f}};

  for (int k0 = 0; k0 < K; k0 += 16) {
    if (aMc) {
      #pragma unroll
      for (int i = tid; i < 1024; i += 256) {
        int m = i & 63, kk = i >> 6;
        int mm = m0 + m, kg = k0 + kk;
        As[kk][m] = (mm < M && kg < K) ? A[(long)mm * sAm + (long)kg * sAk] : 0.f;
      }
    } else {
      #pragma unroll
      for (int i = tid; i < 1024; i += 256) {
        int kk = i & 15, m = i >> 4;
        int mm = m0 + m, kg = k0 + kk;
        As[kk][m] = (mm < M && kg < K) ? A[(long)mm * sAm + (long)kg * sAk] : 0.f;
      }
    }
    if (bNc) {
      #pragma unroll
      for (int i = tid; i < 1024; i += 256) {
        int n = i & 63, kk = i >> 6;
        int nn = n0 + n, kg = k0 + kk;
        Bs[kk][n] = (nn < Nn && kg < K) ? B[(long)kg * sBk + (long)nn * sBn] : 0.f;
      }
    } else {
      #pragma unroll
      for (int i = tid; i < 1024; i += 256) {
        int kk = i & 15, n = i >> 4;
        int nn = n0 + n, kg = k0 + kk;
        Bs[kk][n] = (nn < Nn && kg < K) ? B[(long)kg * sBk + (long)nn * sBn] : 0.f;
      }
    }
    __syncthreads();
    #pragma unroll
    for (int kk = 0; kk < 16; ++kk) {
      float4 av = *(const float4*)&As[kk][ty * 4];
      float4 bv = *(const float4*)&Bs[kk][tx * 4];
      float a0 = av.x, a1 = av.y, a2 = av.z, a3 = av.w;
      float b0 = bv.x, b1 = bv.y, b2 = bv.z, b3 = bv.w;
      acc[0][0] += a0 * b0; acc[0][1] += a0 * b1; acc[0][2] += a0 * b2; acc[0][3] += a0 * b3;
      acc[1][0] += a1 * b0; acc[1][1] += a1 * b1; acc[1][2] += a1 * b2; acc[1][3] += a1 * b3;
      acc[2][0] += a2 * b0; acc[2][1] += a2 * b1; acc[2][2] += a2 * b2; acc[2][3] += a2 * b3;
      acc[3][0] += a3 * b0; acc[3][1] += a3 * b1; acc[3][2] += a3 * b2; acc[3][3] += a3 * b3;
    }
    __syncthreads();
  }
  #pragma unroll
  for (int i = 0; i < 4; ++i) {
    int mm = m0 + ty * 4 + i;
    if (mm >= M) continue;
    float bb = bias ? bias[mm] : 0.f;
    #pragma unroll
    for (int j = 0; j < 4; ++j) {
      int nn = n0 + tx * 4 + j;
      if (nn < Nn) Y[(long)mm * sYm + (long)nn * sYn] = acc[i][j] + bb;
    }
  }
}

// ---------------- im2col for SAME 3x3 over xp (channels 0..255 of xa) -------
__global__ __launch_bounds__(256) void im2col_same(
    const float* __restrict__ xa, float* __restrict__ icol, int nb, long total)
{
  long i = (long)blockIdx.x * 256 + threadIdx.x;
  if (i >= total) return;
  int q = (int)(i % 1600); long r = i / 1600;
  int k = (int)(r % 2304); int nn = (int)(r / 2304);
  int c = k / 9, tap = k - c * 9;
  int dy = tap / 3, dx = tap - dy * 3;
  int qy = q / 40, qx = q - qy * 40;
  int y = qy + dy - 1, x = qx + dx - 1;
  float v = 0.f;
  if (y >= 0 && y < 40 && x >= 0 && x < 40)
    v = xa[(long)(nb + nn) * 1228800 + (long)c * 1600 + y * 40 + x];
  icol[i] = v;
}

// crop SAME-conv output (interior) -> VALID-indexed k_x / v_x buffers
__global__ __launch_bounds__(256) void crop_kv(
    const float* __restrict__ kvs, float* __restrict__ kx, float* __restrict__ vx,
    long total)
{
  long i = (long)blockIdx.x * 256 + threadIdx.x;
  if (i >= total) return;
  int d = (int)(i % 1444); long r = i / 1444;
  int cc = (int)(r % 512); int n = (int)(r / 512);
  int yv = d / 38, xv = d - yv * 38;
  float v = kvs[(long)n * 819200 + (long)cc * 1600 + (yv + 1) * 40 + (xv + 1)];
  if (cc < 256) kx[(long)n * 369664 + (long)cc * 1444 + d] = v;
  else          vx[(long)n * 369664 + (long)(cc - 256) * 1444 + d] = v;
}

// ---------------- step-1 uniform-h class tables -----------------------------
// j<9: q_h1[j][a] (tap-validity class j = uy*3+ux); j==9: k_h1[a]; j==10: v_h1[a]
__global__ __launch_bounds__(64) void uniform_kv_kern(
    const float* __restrict__ h0, const float* __restrict__ w_qh,
    const float* __restrict__ w_kh, const float* __restrict__ w_vh,
    float* __restrict__ qh1, float* __restrict__ kh1, float* __restrict__ vh1)
{
  int a = blockIdx.x, j = blockIdx.y, t = threadIdx.x;
  const float* wsel = (j < 9) ? w_qh : (j == 9) ? w_kh : w_vh;
  bool dyok0 = true, dyok2 = true, dxok0 = true, dxok2 = true;
  if (j < 9) {
    int uy = j / 3, ux = j - uy * 3;
    dyok0 = (uy != 0); dyok2 = (uy != 2);   // y==0: dy=0 pad-invalid; y==39: dy=2
    dxok0 = (ux != 0); dxok2 = (ux != 2);
  }
  float acc = 0.f;
  for (int c = t; c < 256; c += 64) {
    const float* wp = wsel + a * 2304 + c * 9;
    float s = 0.f;
    #pragma unroll
    for (int dy = 0; dy < 3; ++dy) {
      if ((dy == 0 && !dyok0) || (dy == 2 && !dyok2)) continue;
      #pragma unroll
      for (int dx = 0; dx < 3; ++dx) {
        if ((dx == 0 && !dxok0) || (dx == 2 && !dxok2)) continue;
        s += wp[dy * 3 + dx];
      }
    }
    acc += s * h0[c];
  }
  #pragma unroll
  for (int o = 32; o; o >>= 1) acc += __shfl_down(acc, o);
  if (t == 0) {
    if (j < 9) qh1[j * 256 + a] = acc;
    else if (j == 9) kh1[a] = acc;
    else vh1[a] = acc;
  }
}

// ---------------- row softmax (in place) ------------------------------------
__global__ __launch_bounds__(256) void softmax_rows(float* __restrict__ p, int L)
{
  float* r = p + (long)blockIdx.x * L;
  int t = threadIdx.x;
  __shared__ float redm[4], reds[4];
  float mx = -3.4e38f;
  for (int i = t; i < L; i += 256) mx = fmaxf(mx, r[i]);
  #pragma unroll
  for (int o = 32; o; o >>= 1) mx = fmaxf(mx, __shfl_down(mx, o));
  if ((t & 63) == 0) redm[t >> 6] = mx;
  __syncthreads();
  mx = fmaxf(fmaxf(redm[0], redm[1]), fmaxf(redm[2], redm[3]));
  float s = 0.f;
  for (int i = t; i < L; i += 256) { float v = expf(r[i] - mx); r[i] = v; s += v; }
  #pragma unroll
  for (int o = 32; o; o >>= 1) s += __shfl_down(s, o);
  if ((t & 63) == 0) reds[t >> 6] = s;
  __syncthreads();
  float inv = 1.f / (reds[0] + reds[1] + reds[2] + reds[3]);
  for (int i = t; i < L; i += 256) r[i] *= inv;
}

// ---------------- gate input vector: [a10 ; v_h1] laid out [n][k512][u9] ----
__global__ __launch_bounds__(256) void build_vecb(
    const float* __restrict__ a10, const float* __restrict__ vh1,
    float* __restrict__ vecb)
{
  int i = blockIdx.x * 256 + threadIdx.x;
  if (i >= 8 * 512 * 9) return;
  int u = i % 9; int k = (i / 9) % 512; int n = i / 4608;
  vecb[i] = (k < 256) ? a10[n * 2304 + u * 256 + k] : vh1[k - 256];
}

// h1 = z*h0 + (1-z)*tanh(hpre), classed [n][hc][u9]
__global__ __launch_bounds__(256) void gate_ew(
    const float* __restrict__ zpre, const float* __restrict__ hpre,
    const float* __restrict__ h0, float* __restrict__ h1)
{
  int i = blockIdx.x * 256 + threadIdx.x;
  if (i >= 8 * 256 * 9) return;
  int hc = (i % 2304) / 9;
  float z = 1.f / (1.f + expf(-zpre[i]));
  float hv = tanhf(hpre[i]);
  h1[i] = z * h0[hc] + (1.f - z) * hv;
}

// im2col-on-classes for the step-2 VALID conv over piecewise-constant h1:
// G[n][(c,dy,dx)][t9] = h1[n][c][class-of-window-row/col]
__global__ __launch_bounds__(256) void build_G(
    const float* __restrict__ h1, float* __restrict__ G)
{
  int i = blockIdx.x * 256 + threadIdx.x;
  if (i >= 8 * 2304 * 9) return;
  int t = i % 9; int k = (i / 9) % 2304; int n = i / 20736;
  int c = k / 9, tap = k - c * 9, dy = tap / 3, dx = tap - dy * 3;
  int ty = t / 3, tx = t - ty * 3;
  int uy = (ty == 0) ? (dy == 0 ? 0 : 1) : (ty == 2) ? (dy == 2 ? 2 : 1) : 1;
  int ux = (tx == 0) ? (dx == 0 ? 0 : 1) : (tx == 2) ? (dx == 2 ? 2 : 1) : 1;
  G[i] = h1[n * 2304 + c * 9 + uy * 3 + ux];
}

// step-2 (a=0,b=1) classed attention: 9 logits per query, mult {1,36,1}^2,
// writes a01 into xa channels 512..767.
__global__ __launch_bounds__(256) void attn_b1(
    const float* __restrict__ qx, const float* __restrict__ khc,
    const float* __restrict__ vhc, float* __restrict__ xa)
{
  __shared__ float ks[2304];
  __shared__ float vs[2304];
  int n = blockIdx.y;
  int q = blockIdx.x * 256 + threadIdx.x;
  const float* kp = khc + n * 2304;
  const float* vp = vhc + n * 2304;
  for (int i = threadIdx.x; i < 2304; i += 256) { ks[i] = kp[i]; vs[i] = vp[i]; }
  __syncthreads();
  bool act = (q < 1600);
  float L[9] = {0.f, 0.f, 0.f, 0.f, 0.f, 0.f, 0.f, 0.f, 0.f};
  const float* qp = qx + (long)n * 409600 + q;
  for (int c = 0; c < 256; ++c) {
    float qv = act ? qp[(long)c * 1600] : 0.f;
    #pragma unroll
    for (int t = 0; t < 9; ++t) L[t] += qv * ks[c * 9 + t];
  }
  float mx = L[0];
  #pragma unroll
  for (int t = 1; t < 9; ++t) mx = fmaxf(mx, L[t]);
  float e[9]; float Z = 0.f;
  #pragma unroll
  for (int t = 0; t < 9; ++t) {
    float m = ((t / 3) == 1 ? 36.f : 1.f) * ((t % 3) == 1 ? 36.f : 1.f);
    e[t] = m * expf(L[t] - mx);
    Z += e[t];
  }
  float inv = 1.f / Z;
  #pragma unroll
  for (int t = 0; t < 9; ++t) e[t] *= inv;
  float* op = xa + (long)n * 1228800 + 819200 + q;   // channels 512..767
  for (int p = 0; p < 256; ++p) {
    float s = 0.f;
    #pragma unroll
    for (int t = 0; t < 9; ++t) s += e[t] * vs[p * 9 + t];
    if (act) op[(long)p * 1600] = s;
  }
}

// ---------------------------------------------------------------------------
extern "C" void kernel_launch(void* const* d_in, const int* in_sizes, int n_in,
                              void* d_out, int out_size, void* d_ws, size_t ws_size,
                              hipStream_t stream)
{
  const float* x     = (const float*)d_in[0];
  const float* h0    = (const float*)d_in[1];
  const float* w_px  = (const float*)d_in[2];
  const float* b_px  = (const float*)d_in[3];
  const float* w_qx  = (const float*)d_in[4];
  const float* w_qh  = (const float*)d_in[5];
  const float* w_kx  = (const float*)d_in[6];
  const float* w_kh  = (const float*)d_in[7];
  const float* w_vx  = (const float*)d_in[8];
  const float* w_vh  = (const float*)d_in[9];
  const float* w_z   = (const float*)d_in[10];
  const float* b_z   = (const float*)d_in[11];
  const float* w_h   = (const float*)d_in[12];
  const float* b_h   = (const float*)d_in[13];
  const float* w_out = (const float*)d_in[14];
  const float* b_out = (const float*)d_in[15];
  float* out = (float*)d_out;
  float* ws  = (float*)d_ws;

  // ---- workspace layout (floats, 64-float aligned) ----
  size_t off = 0;
  auto alloc = [&](size_t n) { size_t o = off; off += (n + 63) & ~(size_t)63; return o; };
  float* xa   = ws + alloc((size_t)8 * 768 * 1600);  // [n][768ch][1600]: xp|a00|a01
  float* qx   = ws + alloc((size_t)8 * 256 * 1600);
  float* kx   = ws + alloc((size_t)8 * 256 * 1444);
  float* vx   = ws + alloc((size_t)8 * 256 * 1444);
  float* qh1  = ws + alloc(9 * 256);
  float* kh1  = ws + alloc(256);
  float* vh1  = ws + alloc(256);
  float* L0   = ws + alloc((size_t)8 * 9 * 1444);
  float* a10  = ws + alloc((size_t)8 * 9 * 256);
  float* vecb = ws + alloc((size_t)8 * 512 * 9);
  float* zpre = ws + alloc((size_t)8 * 256 * 9);
  float* hpre = ws + alloc((size_t)8 * 256 * 9);
  float* h1   = ws + alloc((size_t)8 * 256 * 9);
  float* G    = ws + alloc((size_t)8 * 2304 * 9);
  float* khc  = ws + alloc((size_t)8 * 256 * 9);
  float* vhc  = ws + alloc((size_t)8 * 256 * 9);
  float* scratch = ws + off;
  long avail_f = (long)(ws_size / 4) - (long)off;
  if (avail_f < 0) avail_f = 0;
  int cn = (int)(avail_f / 4505600L); if (cn < 1) cn = 1; if (cn > 8) cn = 8;
  int an = (int)(avail_f / 2310400L); if (an < 1) an = 1; if (an > 8) an = 8;

  auto gemm = [&](dim3 grid,
                  const float* A, long sAm, long sAk, long sAb,
                  const float* B, long sBk, long sBn, long sBb,
                  float* Y, long sYm, long sYn, long sYb,
                  const float* bias, int M, int Nn, int K, int aMc, int bNc) {
    gemm64<<<grid, dim3(256), 0, stream>>>(A, sAm, sAk, sAb, B, sBk, sBn, sBb,
                                           Y, sYm, sYn, sYb, bias, M, Nn, K, aMc, bNc);
  };

  // ---- 1) xp = w_px . x + b_px  -> xa channels 0..255 ----
  gemm(dim3(25, 4, 8), w_px, 128, 1, 0, x, 1600, 1, 204800,
       xa, 1600, 1, 1228800, b_px, 256, 1600, 128, 0, 1);

  // ---- 2) q_x / k_x / v_x via im2col + GEMM (SAME, then crop k/v) ----
  {
    float* icol = scratch;
    float* kvs  = scratch + (size_t)cn * 3686400;
    for (int nb = 0; nb < 8; nb += cn) {
      int c = (8 - nb < cn) ? (8 - nb) : cn;
      long tot = (long)c * 3686400;
      im2col_same<<<dim3((unsigned)((tot + 255) / 256)), dim3(256), 0, stream>>>(xa, icol, nb, tot);
      gemm(dim3(25, 4, c), w_qx, 2304, 1, 0, icol, 1600, 1, 3686400,
           qx + (size_t)nb * 409600, 1600, 1, 409600, nullptr, 256, 1600, 2304, 0, 1);
      gemm(dim3(25, 4, c), w_kx, 2304, 1, 0, icol, 1600, 1, 3686400,
           kvs, 1600, 1, 819200, nullptr, 256, 1600, 2304, 0, 1);
      gemm(dim3(25, 4, c), w_vx, 2304, 1, 0, icol, 1600, 1, 3686400,
           kvs + 409600, 1600, 1, 819200, nullptr, 256, 1600, 2304, 0, 1);
      long ctot = (long)c * 512 * 1444;
      crop_kv<<<dim3((unsigned)((ctot + 255) / 256)), dim3(256), 0, stream>>>(
          kvs, kx + (size_t)nb * 369664, vx + (size_t)nb * 369664, ctot);
    }
  }

  // ---- 3) step-1 class tables ----
  uniform_kv_kern<<<dim3(256, 11), dim3(64), 0, stream>>>(h0, w_qh, w_kh, w_vh, qh1, kh1, vh1);

  // step-1 (a=1,b=0): L0[n][u9][d] = qh1 . k_x
  gemm(dim3(23, 1, 8), qh1, 256, 1, 0, kx, 1444, 1, 369664,
       L0, 1444, 1, 12996, nullptr, 9, 1444, 256, 0, 1);
  softmax_rows<<<dim3(72), dim3(256), 0, stream>>>(L0, 1444);
  // a10[n][u][p] = v_x . wt
  gemm(dim3(1, 4, 8), vx, 1444, 1, 369664, L0, 1, 1444, 12996,
       a10, 1, 256, 2304, nullptr, 256, 9, 1444, 0, 0);

  // gates on 9 classes: zpre/hpre[n][hc][u] = W.[a10; v_h1] + b
  build_vecb<<<dim3(144), dim3(256), 0, stream>>>(a10, vh1, vecb);
  gemm(dim3(1, 4, 8), w_z, 512, 1, 0, vecb, 9, 1, 4608,
       zpre, 9, 1, 2304, b_z, 256, 9, 512, 0, 1);
  gemm(dim3(1, 4, 8), w_h, 512, 1, 0, vecb, 9, 1, 4608,
       hpre, 9, 1, 2304, b_h, 256, 9, 512, 0, 1);
  gate_ew<<<dim3(72), dim3(256), 0, stream>>>(zpre, hpre, h0, h1);

  // ---- 4) step-2 classed k_h2/v_h2 (VALID conv on piecewise-constant h1) ----
  build_G<<<dim3(648), dim3(256), 0, stream>>>(h1, G);
  gemm(dim3(1, 4, 8), w_kh, 2304, 1, 0, G, 9, 1, 20736,
       khc, 9, 1, 2304, nullptr, 256, 9, 2304, 0, 1);
  gemm(dim3(1, 4, 8), w_vh, 2304, 1, 0, G, 9, 1, 20736,
       vhc, 9, 1, 2304, nullptr, 256, 9, 2304, 0, 1);

  // step-2 (a=0,b=1) classed attention -> xa channels 512..767
  attn_b1<<<dim3(7, 8), dim3(256), 0, stream>>>(qx, khc, vhc, xa);

  // ---- 5) step-2 (a=0,b=0) full attention -> xa channels 256..511 ----
  for (int nb = 0; nb < 8; nb += an) {
    int c = (8 - nb < an) ? (8 - nb) : an;
    gemm(dim3(23, 25, c), qx + (size_t)nb * 409600, 1, 1600, 409600,
         kx + (size_t)nb * 369664, 1444, 1, 369664,
         scratch, 1444, 1, 2310400, nullptr, 1600, 1444, 256, 1, 1);
    softmax_rows<<<dim3(c * 1600), dim3(256), 0, stream>>>(scratch, 1444);
    gemm(dim3(25, 4, c), vx + (size_t)nb * 369664, 1444, 1, 369664,
         scratch, 1, 1444, 2310400,
         xa + (size_t)nb * 1228800 + 409600, 1600, 1, 1228800,
         nullptr, 256, 1600, 1444, 0, 0);
  }

  // ---- 6) out = w_out . [xp; a00; a01] + b_out ----
  gemm(dim3(25, 4, 8), w_out, 768, 1, 0, xa, 1600, 1, 1228800,
       out, 1600, 1, 409600, b_out, 256, 1600, 768, 0, 1);
}